// Round 12
// baseline (148.727 us; speedup 1.0000x reference)
//
#include <hip/hip_runtime.h>

#define NBINS 101
#define NB2 (2 * NBINS)    // 202 bins total (pos + neg)
#define NTHREADS 256
#define NCOPY 16           // histogram replicas, one per lane&15
#define CNT_SHIFT 21       // count 11 bits | frac 10 bits
#define QMAXF 103423.0f    // (100<<10)|1023, exact in fp32
#define FSCALE 226.2741699796952f   // sqrt(50 * 1024): folds (s+1)*51200 into MFMA

typedef _Float16 half8 __attribute__((ext_vector_type(8)));
typedef float floatx4 __attribute__((ext_vector_type(4)));

// ---------------------------------------------------------------------------
// R12: occupancy is structurally capped at ~8 waves/CU by 64x64 jobs (2080
// jobs / 256 CU); R11 proved LESS parallelism hurts a stall-bound kernel.
// Shrink jobs to 32x32 tiles: 8256 jobs = 2064 blocks x 4 waves -> ~8
// blocks/CU, 32 waves/CU (4x R10). acc = 2x2 frags (16 VGPR) so
// launch_bounds(256,8) fits; LDS ~14 KB (NCOPY 16; overflow: <=256 adds per
// (bin,copy)/block -> count < 2^11, sum(frac) < 2^18). R8/R9/R10 showed
// dispatch gaps are cheap -> back to 3 dispatches, no handshake: hist plain-
// stores a transposed partials[bin][block] row, reduce reads contiguously.
// ---------------------------------------------------------------------------

__global__ __launch_bounds__(NTHREADS)
void prep_kernel(const float* __restrict__ feats,
                 const int* __restrict__ classes,
                 _Float16* __restrict__ wsF,
                 unsigned char* __restrict__ wsC,
                 int ngroups,   // N*D/8 groups of 8 floats
                 int n) {       // N (classes)
    int t = blockIdx.x * NTHREADS + threadIdx.x;
    if (t < ngroups) {
        const float4* p = (const float4*)feats + (size_t)t * 2;
        float4 f0 = p[0];
        float4 f1 = p[1];
        half8 h;
        h[0] = (_Float16)(f0.x * FSCALE); h[1] = (_Float16)(f0.y * FSCALE);
        h[2] = (_Float16)(f0.z * FSCALE); h[3] = (_Float16)(f0.w * FSCALE);
        h[4] = (_Float16)(f1.x * FSCALE); h[5] = (_Float16)(f1.y * FSCALE);
        h[6] = (_Float16)(f1.z * FSCALE); h[7] = (_Float16)(f1.w * FSCALE);
        *(half8*)(wsF + (size_t)t * 8) = h;
    }
    if (t < n) wsC[t] = (unsigned char)classes[t];
}

// one 32x32 upper-triangular tile per wave; 2064 blocks x 4 waves = 8256 jobs
__global__ __launch_bounds__(NTHREADS, 8)
void hist_pairs_kernel(const _Float16* __restrict__ feats16,
                       const unsigned char* __restrict__ cls8,
                       float* __restrict__ partials,  // [NB2][nblocks] transposed
                       int ntiles, int nblocks) {
    __shared__ unsigned lhist[NB2][NCOPY];   // packed count|frac, 12.9 KB
    __shared__ float Fbuf[NB2];
    __shared__ __align__(16) int cls[4][2][32];  // [wave][A/B][row] wave-private

    const int tid = threadIdx.x;
    const int wave = tid >> 6;
    const int lane = tid & 63;
    const int lr = lane & 15;
    const int quad = lane >> 4;
    const int copy = lane & (NCOPY - 1);

    // zero local histograms (808 uint4)
    {
        uint4* z = (uint4*)&lhist[0][0];
        uint4 zero = {0u, 0u, 0u, 0u};
        for (int t = tid; t < NB2 * NCOPY / 4; t += NTHREADS) z[t] = zero;
    }
    __syncthreads();

    // job -> (ti, tj): analytic inverse of S(t) = t*M - t*(t-1)/2, + fixup
    const int job = blockIdx.x * 4 + wave;   // grid sized exactly: job < njobs
    const int M = ntiles;
    int ti;
    {
        const int A = 2 * M + 1;
        float disc = (float)(A * A - 8 * job);
        ti = (int)(((float)A - sqrtf(disc)) * 0.5f);
        if (ti < 0) ti = 0;
        if (ti > M - 1) ti = M - 1;
        // S(t) = t*M - t*(t-1)/2
        while (ti * M - ((ti * (ti - 1)) >> 1) > job) --ti;
        while ((ti + 1) * M - (((ti + 1) * ti) >> 1) <= job) ++ti;
    }
    const int tj = ti + (job - (ti * M - ((ti * (ti - 1)) >> 1)));
    const int i0 = ti * 32, j0 = tj * 32;

    // wave-private class staging: same-wave LDS RAW, no block barrier
    if (lane < 32) cls[wave][0][lane] = cls8[i0 + lane];
    else           cls[wave][1][lane - 32] = cls8[j0 + lane - 32];

    const _Float16* Ab = feats16 + (size_t)(i0 + lr) * 128 + quad * 8;
    const _Float16* Bb = feats16 + (size_t)(j0 + lr) * 128 + quad * 8;

    // acc init = binning bias: (s+1)*51200 + 0.5 rounding
    floatx4 acc[2][2];
    #pragma unroll
    for (int mi = 0; mi < 2; ++mi)
        #pragma unroll
        for (int ni = 0; ni < 2; ++ni) {
            acc[mi][ni][0] = 51200.5f; acc[mi][ni][1] = 51200.5f;
            acc[mi][ni][2] = 51200.5f; acc[mi][ni][3] = 51200.5f;
        }

    #pragma unroll
    for (int ks = 0; ks < 128; ks += 32) {
        half8 af[2], bf[2];
        #pragma unroll
        for (int mi = 0; mi < 2; ++mi)
            af[mi] = *(const half8*)(Ab + (size_t)mi * 16 * 128 + ks);
        #pragma unroll
        for (int ni = 0; ni < 2; ++ni)
            bf[ni] = *(const half8*)(Bb + (size_t)ni * 16 * 128 + ks);
        #pragma unroll
        for (int mi = 0; mi < 2; ++mi)
            #pragma unroll
            for (int ni = 0; ni < 2; ++ni)
                acc[mi][ni] = __builtin_amdgcn_mfma_f32_16x16x32_f16(
                    af[mi], bf[ni], acc[mi][ni], 0, 0, 0);
    }

    // classes for this lane's C fragment rows/cols
    int cA[2][4], cB[2];
    #pragma unroll
    for (int mi = 0; mi < 2; ++mi) {
        int4 c4 = *(const int4*)&cls[wave][0][mi * 16 + quad * 4];
        cA[mi][0] = c4.x; cA[mi][1] = c4.y;
        cA[mi][2] = c4.z; cA[mi][3] = c4.w;
    }
    #pragma unroll
    for (int ni = 0; ni < 2; ++ni) cB[ni] = cls[wave][1][ni * 16 + lr];

    // binning: one ds_add_u32 per pair. C-layout col=lane&15, row=quad*4+reg
    unsigned* hb = &lhist[0][0] + copy;
    const bool diag = (ti == tj);
    #pragma unroll
    for (int mi = 0; mi < 2; ++mi) {
        #pragma unroll
        for (int ni = 0; ni < 2; ++ni) {
            #pragma unroll
            for (int r = 0; r < 4; ++r) {
                const int li = mi * 16 + quad * 4 + r;
                const int lj = ni * 16 + lr;
                if (diag && li >= lj) continue;  // strict upper triangle
                float qf = fminf(fmaxf(acc[mi][ni][r], 0.0f), QMAXF);
                unsigned q = (unsigned)qf;
                unsigned idx = q >> 10;
                unsigned word = (q & 1023u) | (1u << CNT_SHIFT);
                unsigned hoff = (cA[mi][r] == cB[ni]) ? 0u : (unsigned)NBINS;
                atomicAdd(hb + (hoff + idx) * NCOPY, word);
            }
        }
    }
    __syncthreads();

    // unpack: C = sum(w>>21), F = sum(w & (2^21-1))/1024, telescope per
    // 101-bin segment, store to TRANSPOSED partials[bin][block]
    const int t = tid;
    float myC = 0.0f, myF = 0.0f;
    if (t < NB2) {
        unsigned Cs = 0, Fq = 0;
        #pragma unroll
        for (int c = 0; c < NCOPY; ++c) {
            unsigned w = lhist[t][(c + t) & (NCOPY - 1)];
            Cs += w >> CNT_SHIFT;
            Fq += w & ((1u << CNT_SHIFT) - 1);
        }
        myC = (float)Cs;
        myF = (float)Fq * (1.0f / 1024.0f);
        Fbuf[t] = myF;
    }
    __syncthreads();
    if (t < NB2) {
        const int lo = (t < NBINS) ? 0 : NBINS;
        const int hi = lo + NBINS - 1;
        float h = myC;
        if (t < hi) h -= myF;
        if (t > lo) h += Fbuf[t - 1];
        partials[(size_t)t * nblocks + blockIdx.x] = h;
    }
}

// ---------------------------------------------------------------------------
// Sum transposed partials (contiguous per bin, float4), then fp64 finalize.
// ---------------------------------------------------------------------------
__global__ __launch_bounds__(1024)
void reduce_finalize_kernel(const float* __restrict__ partials,
                            float* __restrict__ out, int nblocks) {
    __shared__ float acc[NB2][5];
    __shared__ float h[NB2];
    const int t = threadIdx.x;
    if (t < NB2 * 5) {
        const int bin = t / 5;
        const int g = t - bin * 5;
        const int chunk = ((nblocks + 4) / 5 + 3) & ~3;   // 416 for 2064
        int start = g * chunk;
        int end = start + chunk;
        if (end > nblocks) end = nblocks;
        const float* p = partials + (size_t)bin * nblocks;
        float s = 0.0f;
        int i = start;
        for (; i + 3 < end; i += 4) {
            float4 v = *(const float4*)&p[i];
            s += (v.x + v.y) + (v.z + v.w);
        }
        for (; i < end; ++i) s += p[i];
        acc[bin][g] = s;
    }
    __syncthreads();
    if (t < NB2)
        h[t] = ((acc[t][0] + acc[t][1]) + (acc[t][2] + acc[t][3])) + acc[t][4];
    __syncthreads();
    if (t == 0) {
        double sp = 0.0, sn = 0.0;
        for (int k = 0; k < NBINS; ++k) { sp += h[k]; sn += h[NBINS + k]; }
        double isp = 1.0 / sp, isn = 1.0 / sn;
        double cdf = 0.0, res = 0.0;
        for (int k = 0; k < NBINS; ++k) {
            cdf += (double)h[k] * isp;                 // inclusive cumsum of pos
            res += (double)h[NBINS + k] * isn * cdf;   // dot with neg
        }
        out[0] = (float)res;
    }
}

extern "C" void kernel_launch(void* const* d_in, const int* in_sizes, int n_in,
                              void* d_out, int out_size, void* d_ws, size_t ws_size,
                              hipStream_t stream) {
    const float* feats   = (const float*)d_in[0];
    const int*   classes = (const int*)d_in[1];
    float* out = (float*)d_out;

    int N = in_sizes[1];                       // 4096
    int D = in_sizes[0] / N;                   // 128
    int ntiles = N / 32;                       // 128
    int njobs = ntiles * (ntiles + 1) / 2;     // 8256 wave-jobs
    int nblocks = njobs / 4;                   // 2064 blocks, 4 jobs each, exact

    // workspace layout: f16 scaled feats | u8 classes | fp32 partials (transposed)
    _Float16* wsF = (_Float16*)d_ws;
    unsigned char* wsC = (unsigned char*)(wsF + (size_t)N * D);
    float* partials = (float*)(wsC + ((N + 15) & ~15));

    int ngroups = N * D / 8;                   // 65536 groups of 8 floats
    int cblocks = (ngroups + NTHREADS - 1) / NTHREADS;
    prep_kernel<<<cblocks, NTHREADS, 0, stream>>>(feats, classes, wsF, wsC,
                                                  ngroups, N);
    hist_pairs_kernel<<<nblocks, NTHREADS, 0, stream>>>(wsF, wsC, partials,
                                                        ntiles, nblocks);
    reduce_finalize_kernel<<<1, 1024, 0, stream>>>(partials, out, nblocks);
}

// Round 13
// 86.334 us; speedup vs baseline: 1.7227x; 1.7227x over previous
//
#include <hip/hip_runtime.h>

#define NBINS 101
#define NB2 (2 * NBINS)    // 202 bins total (pos + neg)
#define NTHREADS 256
#define NCOPY 16           // histogram replicas, one per lane&15
#define CNT_SHIFT 21       // count 11 bits | frac 10 bits
#define QMAXF 103423.0f    // (100<<10)|1023, exact in fp32
#define FSCALE 226.2741699796952f   // sqrt(50 * 1024): folds (s+1)*51200 into MFMA

typedef _Float16 half8 __attribute__((ext_vector_type(8)));
typedef float floatx4 __attribute__((ext_vector_type(4)));

// ---------------------------------------------------------------------------
// R13: R12's 32x32-job hist (32 waves/CU) WORKED (hist fell out of top-5);
// the 149us total was the single-block reduce reading 1.67MB latency-bound
// on one CU (81.9us, VALUBusy 0.04%). Fix: parallel reduce, one block per
// bin (each bin contiguous in the transposed partials), wave-shuffle + LDS
// combine, plain store to g_hist; tiny 1-block finalize. Dispatch gaps are
// measured-cheap (R8-R10), so 4 dispatches.
// ---------------------------------------------------------------------------

__global__ __launch_bounds__(NTHREADS)
void prep_kernel(const float* __restrict__ feats,
                 const int* __restrict__ classes,
                 _Float16* __restrict__ wsF,
                 unsigned char* __restrict__ wsC,
                 int ngroups,   // N*D/8 groups of 8 floats
                 int n) {       // N (classes)
    int t = blockIdx.x * NTHREADS + threadIdx.x;
    if (t < ngroups) {
        const float4* p = (const float4*)feats + (size_t)t * 2;
        float4 f0 = p[0];
        float4 f1 = p[1];
        half8 h;
        h[0] = (_Float16)(f0.x * FSCALE); h[1] = (_Float16)(f0.y * FSCALE);
        h[2] = (_Float16)(f0.z * FSCALE); h[3] = (_Float16)(f0.w * FSCALE);
        h[4] = (_Float16)(f1.x * FSCALE); h[5] = (_Float16)(f1.y * FSCALE);
        h[6] = (_Float16)(f1.z * FSCALE); h[7] = (_Float16)(f1.w * FSCALE);
        *(half8*)(wsF + (size_t)t * 8) = h;
    }
    if (t < n) wsC[t] = (unsigned char)classes[t];
}

// one 32x32 upper-triangular tile per wave; 2064 blocks x 4 waves = 8256 jobs
__global__ __launch_bounds__(NTHREADS, 8)
void hist_pairs_kernel(const _Float16* __restrict__ feats16,
                       const unsigned char* __restrict__ cls8,
                       float* __restrict__ partials,  // [NB2][nblocks] transposed
                       int ntiles, int nblocks) {
    __shared__ unsigned lhist[NB2][NCOPY];   // packed count|frac, 12.9 KB
    __shared__ float Fbuf[NB2];
    __shared__ __align__(16) int cls[4][2][32];  // [wave][A/B][row] wave-private

    const int tid = threadIdx.x;
    const int wave = tid >> 6;
    const int lane = tid & 63;
    const int lr = lane & 15;
    const int quad = lane >> 4;
    const int copy = lane & (NCOPY - 1);

    // zero local histograms (808 uint4)
    {
        uint4* z = (uint4*)&lhist[0][0];
        uint4 zero = {0u, 0u, 0u, 0u};
        for (int t = tid; t < NB2 * NCOPY / 4; t += NTHREADS) z[t] = zero;
    }
    __syncthreads();

    // job -> (ti, tj): analytic inverse of S(t) = t*M - t*(t-1)/2, + fixup
    const int job = blockIdx.x * 4 + wave;   // grid sized exactly: job < njobs
    const int M = ntiles;
    int ti;
    {
        const int A = 2 * M + 1;
        float disc = (float)(A * A - 8 * job);
        ti = (int)(((float)A - sqrtf(disc)) * 0.5f);
        if (ti < 0) ti = 0;
        if (ti > M - 1) ti = M - 1;
        // S(t) = t*M - t*(t-1)/2
        while (ti * M - ((ti * (ti - 1)) >> 1) > job) --ti;
        while ((ti + 1) * M - (((ti + 1) * ti) >> 1) <= job) ++ti;
    }
    const int tj = ti + (job - (ti * M - ((ti * (ti - 1)) >> 1)));
    const int i0 = ti * 32, j0 = tj * 32;

    // wave-private class staging: same-wave LDS RAW, no block barrier
    if (lane < 32) cls[wave][0][lane] = cls8[i0 + lane];
    else           cls[wave][1][lane - 32] = cls8[j0 + lane - 32];

    const _Float16* Ab = feats16 + (size_t)(i0 + lr) * 128 + quad * 8;
    const _Float16* Bb = feats16 + (size_t)(j0 + lr) * 128 + quad * 8;

    // acc init = binning bias: (s+1)*51200 + 0.5 rounding
    floatx4 acc[2][2];
    #pragma unroll
    for (int mi = 0; mi < 2; ++mi)
        #pragma unroll
        for (int ni = 0; ni < 2; ++ni) {
            acc[mi][ni][0] = 51200.5f; acc[mi][ni][1] = 51200.5f;
            acc[mi][ni][2] = 51200.5f; acc[mi][ni][3] = 51200.5f;
        }

    #pragma unroll
    for (int ks = 0; ks < 128; ks += 32) {
        half8 af[2], bf[2];
        #pragma unroll
        for (int mi = 0; mi < 2; ++mi)
            af[mi] = *(const half8*)(Ab + (size_t)mi * 16 * 128 + ks);
        #pragma unroll
        for (int ni = 0; ni < 2; ++ni)
            bf[ni] = *(const half8*)(Bb + (size_t)ni * 16 * 128 + ks);
        #pragma unroll
        for (int mi = 0; mi < 2; ++mi)
            #pragma unroll
            for (int ni = 0; ni < 2; ++ni)
                acc[mi][ni] = __builtin_amdgcn_mfma_f32_16x16x32_f16(
                    af[mi], bf[ni], acc[mi][ni], 0, 0, 0);
    }

    // classes for this lane's C fragment rows/cols
    int cA[2][4], cB[2];
    #pragma unroll
    for (int mi = 0; mi < 2; ++mi) {
        int4 c4 = *(const int4*)&cls[wave][0][mi * 16 + quad * 4];
        cA[mi][0] = c4.x; cA[mi][1] = c4.y;
        cA[mi][2] = c4.z; cA[mi][3] = c4.w;
    }
    #pragma unroll
    for (int ni = 0; ni < 2; ++ni) cB[ni] = cls[wave][1][ni * 16 + lr];

    // binning: one ds_add_u32 per pair. C-layout col=lane&15, row=quad*4+reg
    unsigned* hb = &lhist[0][0] + copy;
    const bool diag = (ti == tj);
    #pragma unroll
    for (int mi = 0; mi < 2; ++mi) {
        #pragma unroll
        for (int ni = 0; ni < 2; ++ni) {
            #pragma unroll
            for (int r = 0; r < 4; ++r) {
                const int li = mi * 16 + quad * 4 + r;
                const int lj = ni * 16 + lr;
                if (diag && li >= lj) continue;  // strict upper triangle
                float qf = fminf(fmaxf(acc[mi][ni][r], 0.0f), QMAXF);
                unsigned q = (unsigned)qf;
                unsigned idx = q >> 10;
                unsigned word = (q & 1023u) | (1u << CNT_SHIFT);
                unsigned hoff = (cA[mi][r] == cB[ni]) ? 0u : (unsigned)NBINS;
                atomicAdd(hb + (hoff + idx) * NCOPY, word);
            }
        }
    }
    __syncthreads();

    // unpack: C = sum(w>>21), F = sum(w & (2^21-1))/1024, telescope per
    // 101-bin segment, store to TRANSPOSED partials[bin][block]
    const int t = tid;
    float myC = 0.0f, myF = 0.0f;
    if (t < NB2) {
        unsigned Cs = 0, Fq = 0;
        #pragma unroll
        for (int c = 0; c < NCOPY; ++c) {
            unsigned w = lhist[t][(c + t) & (NCOPY - 1)];
            Cs += w >> CNT_SHIFT;
            Fq += w & ((1u << CNT_SHIFT) - 1);
        }
        myC = (float)Cs;
        myF = (float)Fq * (1.0f / 1024.0f);
        Fbuf[t] = myF;
    }
    __syncthreads();
    if (t < NB2) {
        const int lo = (t < NBINS) ? 0 : NBINS;
        const int hi = lo + NBINS - 1;
        float h = myC;
        if (t < hi) h -= myF;
        if (t > lo) h += Fbuf[t - 1];
        partials[(size_t)t * nblocks + blockIdx.x] = h;
    }
}

// ---------------------------------------------------------------------------
// Parallel reduce: one block per bin; bin's partials are contiguous.
// float4 strided loads -> wave shuffle reduce -> LDS combine -> g_hist[bin].
// ---------------------------------------------------------------------------
__global__ __launch_bounds__(NTHREADS)
void reduce_kernel(const float* __restrict__ partials,
                   float* __restrict__ g_hist, int nblocks) {
    __shared__ float wsum[4];
    const int bin = blockIdx.x;
    const int tid = threadIdx.x;
    const float* p = partials + (size_t)bin * nblocks;

    float s = 0.0f;
    const int nvec = nblocks >> 2;               // nblocks % 4 == 0 (2064)
    for (int i = tid; i < nvec; i += NTHREADS) {
        float4 v = *(const float4*)&p[i * 4];
        s += (v.x + v.y) + (v.z + v.w);
    }
    // wave reduction
    #pragma unroll
    for (int off = 32; off > 0; off >>= 1)
        s += __shfl_down(s, off, 64);
    if ((tid & 63) == 0) wsum[tid >> 6] = s;
    __syncthreads();
    if (tid == 0)
        g_hist[bin] = (wsum[0] + wsum[1]) + (wsum[2] + wsum[3]);
}

// ---------------------------------------------------------------------------
// Tiny finalize: normalize, inclusive cumsum of pos, dot with neg.
// ---------------------------------------------------------------------------
__global__ __launch_bounds__(NTHREADS)
void finalize_kernel(const float* __restrict__ g_hist,
                     float* __restrict__ out) {
    __shared__ float h[NB2];
    const int tid = threadIdx.x;
    if (tid < NB2) h[tid] = g_hist[tid];
    __syncthreads();
    if (tid == 0) {
        double sp = 0.0, sn = 0.0;
        for (int k = 0; k < NBINS; ++k) { sp += h[k]; sn += h[NBINS + k]; }
        double isp = 1.0 / sp, isn = 1.0 / sn;
        double cdf = 0.0, res = 0.0;
        for (int k = 0; k < NBINS; ++k) {
            cdf += (double)h[k] * isp;                 // inclusive cumsum of pos
            res += (double)h[NBINS + k] * isn * cdf;   // dot with neg
        }
        out[0] = (float)res;
    }
}

extern "C" void kernel_launch(void* const* d_in, const int* in_sizes, int n_in,
                              void* d_out, int out_size, void* d_ws, size_t ws_size,
                              hipStream_t stream) {
    const float* feats   = (const float*)d_in[0];
    const int*   classes = (const int*)d_in[1];
    float* out = (float*)d_out;

    int N = in_sizes[1];                       // 4096
    int D = in_sizes[0] / N;                   // 128
    int ntiles = N / 32;                       // 128
    int njobs = ntiles * (ntiles + 1) / 2;     // 8256 wave-jobs
    int nblocks = njobs / 4;                   // 2064 blocks, 4 jobs each, exact

    // workspace: f16 scaled feats | u8 classes | g_hist | partials (transposed)
    _Float16* wsF = (_Float16*)d_ws;
    unsigned char* wsC = (unsigned char*)(wsF + (size_t)N * D);
    float* g_hist = (float*)(wsC + ((N + 15) & ~15));
    float* partials = g_hist + ((NB2 + 3) & ~3);

    int ngroups = N * D / 8;                   // 65536 groups of 8 floats
    int cblocks = (ngroups + NTHREADS - 1) / NTHREADS;
    prep_kernel<<<cblocks, NTHREADS, 0, stream>>>(feats, classes, wsF, wsC,
                                                  ngroups, N);
    hist_pairs_kernel<<<nblocks, NTHREADS, 0, stream>>>(wsF, wsC, partials,
                                                        ntiles, nblocks);
    reduce_kernel<<<NB2, NTHREADS, 0, stream>>>(partials, g_hist, nblocks);
    finalize_kernel<<<1, NTHREADS, 0, stream>>>(g_hist, out);
}